// Round 7
// baseline (111.951 us; speedup 1.0000x reference)
//
#include <hip/hip_runtime.h>

namespace {

constexpr int D_DIM   = 512;
constexpr int ENT_LEN = 39;

typedef __attribute__((ext_vector_type(4))) float f32x4;
typedef __attribute__((ext_vector_type(2))) float f32x2;

// ---- fused bf16 table row offsets (rows of 512 bf16 = 1 KB each) ----
constexpr int R_SP    = 0;                 // 1280: W_species[r] + sum(all 9 biases)
constexpr int R_AB    = 1280;              // 320
constexpr int R_IT    = 1600;              // 1024
constexpr int R_MV    = 2624;              // 1792: mv rows 0..895, pp rows 896..1791
constexpr int R_LV    = 4416;              // 101: bits(lv)@W_level + (lv/100)W_feats[0]
constexpr int R_HP    = 4517;              // 1024: bits(hp)@W_hp + (hp/1023)W_feats[1]
constexpr int R_VOL   = 5541;              // 4*256 pair tables
constexpr int R_V4TS  = 6565;              // 512: volcol8(16) x toxic(8) x sleep(4)
constexpr int R_BST   = 7077;              // 3*169 boost-pair tables
constexpr int R_B3GS  = 7584;              // 416: boost6(13) x gender(4) x status(8)
constexpr int R_FLAGS = 8000;              // 32: cb,trap,newsw,faint,active bits
constexpr int R_TOTAL = 8032;
constexpr size_t WS_NEED = (size_t)R_TOTAL * D_DIM * sizeof(unsigned short);

__device__ inline unsigned short f2bf(float f) {      // round-to-nearest-even
    unsigned u = __float_as_uint(f);
    u += 0x7fffu + ((u >> 16) & 1u);
    return (unsigned short)(u >> 16);
}

// ---------------- table precompute: 1 row per block, 2 dims per thread ----------------
__global__ __launch_bounds__(256) void build_tables(
    const float* __restrict__ Wsp, const float* __restrict__ bsp,
    const float* __restrict__ Wab, const float* __restrict__ bab,
    const float* __restrict__ Wit, const float* __restrict__ bit_,
    const float* __restrict__ Wmv, const float* __restrict__ bmv,
    const float* __restrict__ Wlv, const float* __restrict__ blv,
    const float* __restrict__ Whp, const float* __restrict__ bhp,
    const float* __restrict__ Wvo, const float* __restrict__ bvo,
    const float* __restrict__ Wft, const float* __restrict__ bft,
    const float* __restrict__ Wbo, const float* __restrict__ bbo,
    unsigned short* __restrict__ T)
{
    const int r = blockIdx.x;
    const int d = threadIdx.x << 1;
    float vx = 0.f, vy = 0.f;
    auto add = [&](const float* W, int row, float s) {
        const float2 w = *reinterpret_cast<const float2*>(W + (size_t)row * D_DIM + d);
        vx = fmaf(s, w.x, vx); vy = fmaf(s, w.y, vy);
    };
    if (r < R_AB) {
        add(Wsp, r, 1.f);
        add(bsp, 0, 1.f); add(bab, 0, 1.f); add(bit_, 0, 1.f);
        add(bmv, 0, 1.f); add(blv, 0, 1.f); add(bhp, 0, 1.f);
        add(bvo, 0, 1.f); add(bft, 0, 1.f); add(bbo, 0, 1.f);
    } else if (r < R_IT) {
        add(Wab, r - R_AB, 1.f);
    } else if (r < R_MV) {
        add(Wit, r - R_IT, 1.f);
    } else if (r < R_LV) {
        add(Wmv, r - R_MV, 1.f);             // rows 0..895 = mv, 896..1791 = pp
    } else if (r < R_HP) {
        const int lv = r - R_LV;
        for (int b = 0; b < 7; ++b) if ((lv >> b) & 1) add(Wlv, b, 1.f);
        add(Wft, 0, (float)lv * (1.f / 100.f));
    } else if (r < R_VOL) {
        const int hp = r - R_HP;
        for (int b = 0; b < 10; ++b) if ((hp >> b) & 1) add(Whp, b, 1.f);
        add(Wft, 1, (float)hp * (1.f / 1023.f));
    } else if (r < R_V4TS) {
        const int rr = r - R_VOL;              // pair table p: code = v[2p] | v[2p+1]<<4
        const int p = rr >> 8, code = rr & 255, va = code & 15, vb = code >> 4;
        for (int b = 0; b < 4; ++b) {
            if ((va >> b) & 1) add(Wvo, 8 * p + b, 1.f);
            if ((vb >> b) & 1) add(Wvo, 8 * p + 4 + b, 1.f);
        }
    } else if (r < R_BST) {
        const int rr = r - R_V4TS;             // v8(4b) | (tox*4+sl)<<4
        const int v8 = rr & 15, ts = rr >> 4, tox = ts >> 2, sl = ts & 3;
        for (int b = 0; b < 4; ++b) if ((v8 >> b) & 1) add(Wvo, 32 + b, 1.f);
        add(Wbo, 18 + tox, 1.f);
        add(Wbo, 26 + sl, 1.f);
    } else if (r < R_B3GS) {
        const int rr = r - R_BST;              // pair q: code = ba + 13*bb
        const int q = rr / 169, code = rr % 169, ba = code % 13, bb = code / 13;
        add(Wbo, 34 + 26 * q + ba, 1.f);
        add(Wbo, 34 + 26 * q + 13 + bb, 1.f);
        add(Wft, 2 + 2 * q, 0.5f * (float)(ba - 6));
        add(Wft, 3 + 2 * q, 0.5f * (float)(bb - 6));
    } else if (r < R_FLAGS) {
        const int rr = r - R_B3GS;             // b6 + 13*(g*8+s)
        const int b6 = rr % 13, gs = rr / 13, g = gs >> 3, s = gs & 7;
        add(Wbo, 34 + 78 + b6, 1.f);
        add(Wft, 8, 0.5f * (float)(b6 - 6));
        add(Wbo, g, 1.f);
        add(Wbo, 4 + s, 1.f);
    } else {
        const int code = r - R_FLAGS;          // cb*16+tr*8+ns*4+fa*2+ac
        add(Wbo, 12 + ((code >> 4) & 1), 1.f);
        add(Wbo, 14 + ((code >> 3) & 1), 1.f);
        add(Wbo, 16 + ((code >> 2) & 1), 1.f);
        add(Wbo, 30 + ((code >> 1) & 1), 1.f);
        add(Wbo, 32 + (code & 1), 1.f);
    }
    ushort2 o; o.x = f2bf(vx); o.y = f2bf(vy);
    *reinterpret_cast<ushort2*>(T + (size_t)r * D_DIM + d) = o;
}

// -------- main encode: 1 wave = 1 entity; 23 dwordx4 loads, all in flight --------
// Row addresses wave-uniform -> SALU + saddr; accumulators f32x2 -> v_pk_add/fma_f32.
__global__ __launch_bounds__(256, 4) void encode_kernel(
    const int* __restrict__ ent, const unsigned short* __restrict__ T,
    float* __restrict__ out_emb, float* __restrict__ out_mask, int n)
{
    const int w = (blockIdx.x << 2) | (threadIdx.x >> 6);   // wave id = entity id
    if (w >= n) return;
    const int e_idx = __builtin_amdgcn_readfirstlane(w);    // wave-uniform -> SGPR
    const int lane = threadIdx.x & 63;
    const int* __restrict__ e = ent + (size_t)e_idx * ENT_LEN;  // uniform -> s_load
    const char* __restrict__ Tb = reinterpret_cast<const char*>(T);
    const unsigned laneByte = (unsigned)lane << 4;          // 16 B per lane

    auto LD = [&](int row) -> uint4 {
        return *reinterpret_cast<const uint4*>(
            Tb + (((unsigned)row << 10) + laneByte));
    };

    // ---- row indices (SALU) ----
    const int sp = e[0];
    const int mv0 = e[21], mv1 = e[22], mv2 = e[23], mv3 = e[24];

    // ---- issue ALL 23 loads into named registers ----
    const uint4 uSP = LD(R_SP + sp);
    const uint4 uAB = LD(R_AB + e[1]);
    const uint4 uIT = LD(R_IT + e[2]);
    const uint4 uM0 = LD(R_MV + mv0);
    const uint4 uM1 = LD(R_MV + mv1);
    const uint4 uM2 = LD(R_MV + mv2);
    const uint4 uM3 = LD(R_MV + mv3);
    const uint4 uP0 = LD(R_MV + 896 + mv0);
    const uint4 uP1 = LD(R_MV + 896 + mv1);
    const uint4 uP2 = LD(R_MV + 896 + mv2);
    const uint4 uP3 = LD(R_MV + 896 + mv3);
    const uint4 uLV = LD(R_LV + e[3]);
    const uint4 uHP = LD(R_HP + e[4]);
    const uint4 uV0 = LD(R_VOL + (0 << 8) + (e[30] | (e[31] << 4)));
    const uint4 uV1 = LD(R_VOL + (1 << 8) + (e[32] | (e[33] << 4)));
    const uint4 uV2 = LD(R_VOL + (2 << 8) + (e[34] | (e[35] << 4)));
    const uint4 uV3 = LD(R_VOL + (3 << 8) + (e[36] | (e[37] << 4)));
    const uint4 uVT = LD(R_V4TS + e[38] + (((e[10] << 2) + e[11]) << 4));
    const uint4 uB0 = LD(R_BST + 0 * 169 + (e[14] + 6) + 13 * (e[15] + 6));
    const uint4 uB1 = LD(R_BST + 1 * 169 + (e[16] + 6) + 13 * (e[17] + 6));
    const uint4 uB2 = LD(R_BST + 2 * 169 + (e[18] + 6) + 13 * (e[19] + 6));
    const uint4 uBG = LD(R_B3GS + (e[20] + 6) + 13 * ((e[5] << 3) + e[6]));
    const uint4 uFL = LD(R_FLAGS + (e[7] << 4) + (e[8] << 3) + (e[9] << 2) +
                         (e[12] << 1) + e[13]);

    const float s0 = (float)e[25] * (1.f / 1023.f);
    const float s1 = (float)e[26] * (1.f / 1023.f);
    const float s2 = (float)e[27] * (1.f / 1023.f);
    const float s3 = (float)e[28] * (1.f / 1023.f);

    // ---- accumulate (lane covers dims lane*8 .. lane*8+7) ----
    f32x2 c0 = {0.f, 0.f}, c1 = {0.f, 0.f}, c2 = {0.f, 0.f}, c3 = {0.f, 0.f};
    auto UNP = [](unsigned u) -> f32x2 {   // lo exact via shift; hi contaminated (<=2^-8 rel)
        f32x2 r; r.x = __uint_as_float(u << 16); r.y = __uint_as_float(u); return r;
    };
    auto A4 = [&](uint4 u) {
        c0 += UNP(u.x); c1 += UNP(u.y); c2 += UNP(u.z); c3 += UNP(u.w);
    };
    auto F4 = [&](uint4 u, float s) {
        const f32x2 sv = {s, s};
        c0 = __builtin_elementwise_fma(UNP(u.x), sv, c0);
        c1 = __builtin_elementwise_fma(UNP(u.y), sv, c1);
        c2 = __builtin_elementwise_fma(UNP(u.z), sv, c2);
        c3 = __builtin_elementwise_fma(UNP(u.w), sv, c3);
    };

    A4(uSP); A4(uAB); A4(uIT);
    A4(uM0); A4(uM1); A4(uM2); A4(uM3);
    F4(uP0, s0); F4(uP1, s1); F4(uP2, s2); F4(uP3, s3);
    A4(uLV); A4(uHP);
    A4(uV0); A4(uV1); A4(uV2); A4(uV3); A4(uVT);
    A4(uB0); A4(uB1); A4(uB2); A4(uBG);
    A4(uFL);

    const float msk = (sp > 1) ? 1.f : 0.f;
    const f32x2 mk = {msk, msk};
    c0 *= mk; c1 *= mk; c2 *= mk; c3 *= mk;

    f32x4 o0 = {c0.x, c0.y, c1.x, c1.y};
    f32x4 o1 = {c2.x, c2.y, c3.x, c3.y};
    float* op = out_emb + (size_t)e_idx * D_DIM + ((unsigned)lane << 3);
    __builtin_nontemporal_store(o0, reinterpret_cast<f32x4*>(op));
    __builtin_nontemporal_store(o1, reinterpret_cast<f32x4*>(op + 4));
    if (lane == 0) out_mask[e_idx] = msk;
}

// ---------------- fallback (round-0 kernel) if workspace is too small ----------------
__global__ __launch_bounds__(256) void entity_encoder_fallback(
    const int*   __restrict__ ent,
    const float* __restrict__ W_species, const float* __restrict__ b_species,
    const float* __restrict__ W_ability, const float* __restrict__ b_ability,
    const float* __restrict__ W_item,    const float* __restrict__ b_item,
    const float* __restrict__ W_moveset, const float* __restrict__ b_moveset,
    const float* __restrict__ W_level,   const float* __restrict__ b_level,
    const float* __restrict__ W_hp,      const float* __restrict__ b_hp,
    const float* __restrict__ W_vol,     const float* __restrict__ b_vol,
    const float* __restrict__ W_feats,   const float* __restrict__ b_feats,
    const float* __restrict__ W_bool,    const float* __restrict__ b_bool,
    float* __restrict__ out_emb, float* __restrict__ out_mask, int n)
{
    const int e_idx = (blockIdx.x << 1) | (threadIdx.x >> 7);
    if (e_idx >= n) return;
    const int t = threadIdx.x & 127;
    const int d = t << 2;
    const int* __restrict__ e = ent + e_idx * ENT_LEN;
    float4 acc = make_float4(0.f, 0.f, 0.f, 0.f);
#define ADDROW(W, row) do {                                                        \
        const float4 v_ = *reinterpret_cast<const float4*>((W) + ((size_t)(row))*D_DIM + d); \
        acc.x += v_.x; acc.y += v_.y; acc.z += v_.z; acc.w += v_.w;                \
    } while (0)
#define FMAROW(W, row, s) do {                                                     \
        const float4 v_ = *reinterpret_cast<const float4*>((W) + ((size_t)(row))*D_DIM + d); \
        const float s_ = (s);                                                      \
        acc.x = fmaf(s_, v_.x, acc.x); acc.y = fmaf(s_, v_.y, acc.y);              \
        acc.z = fmaf(s_, v_.z, acc.z); acc.w = fmaf(s_, v_.w, acc.w);              \
    } while (0)
    const int sp = e[0];
    ADDROW(W_species, sp); ADDROW(W_ability, e[1]); ADDROW(W_item, e[2]);
    #pragma unroll
    for (int m = 0; m < 4; ++m) {
        const int mv = e[21 + m];
        ADDROW(W_moveset, mv);
        FMAROW(W_moveset, 896 + mv, (float)e[25 + m] * (1.0f / 1023.0f));
    }
    const int lv = e[3];
    #pragma unroll
    for (int b = 0; b < 7; ++b) if ((lv >> b) & 1) ADDROW(W_level, b);
    const int hp = e[4];
    #pragma unroll
    for (int b = 0; b < 10; ++b) if ((hp >> b) & 1) ADDROW(W_hp, b);
    #pragma unroll
    for (int j = 0; j < 9; ++j) {
        const int v = e[30 + j];
        #pragma unroll
        for (int b = 0; b < 4; ++b) if ((v >> b) & 1) ADDROW(W_vol, j * 4 + b);
    }
    FMAROW(W_feats, 0, (float)lv * (1.0f / 100.0f));
    FMAROW(W_feats, 1, (float)hp * (1.0f / 1023.0f));
    #pragma unroll
    for (int i = 0; i < 7; ++i) FMAROW(W_feats, 2 + i, 0.5f * (float)e[14 + i]);
    ADDROW(W_bool, e[5]); ADDROW(W_bool, 4 + e[6]); ADDROW(W_bool, 12 + e[7]);
    ADDROW(W_bool, 14 + e[8]); ADDROW(W_bool, 16 + e[9]); ADDROW(W_bool, 18 + e[10]);
    ADDROW(W_bool, 26 + e[11]); ADDROW(W_bool, 30 + e[12]); ADDROW(W_bool, 32 + e[13]);
    #pragma unroll
    for (int i = 0; i < 7; ++i) ADDROW(W_bool, 34 + 13 * i + e[14 + i] + 6);
    ADDROW(b_species, 0); ADDROW(b_ability, 0); ADDROW(b_item, 0);
    ADDROW(b_moveset, 0); ADDROW(b_level, 0);   ADDROW(b_hp, 0);
    ADDROW(b_vol, 0);     ADDROW(b_feats, 0);   ADDROW(b_bool, 0);
#undef ADDROW
#undef FMAROW
    const bool mask = !(sp == 0 || sp == 1);
    if (!mask) acc = make_float4(0.f, 0.f, 0.f, 0.f);
    *reinterpret_cast<float4*>(out_emb + (size_t)e_idx * D_DIM + d) = acc;
    if (t == 0) out_mask[e_idx] = mask ? 1.0f : 0.0f;
}

} // namespace

extern "C" void kernel_launch(void* const* d_in, const int* in_sizes, int n_in,
                              void* d_out, int out_size, void* d_ws, size_t ws_size,
                              hipStream_t stream) {
    const int n = in_sizes[0] / ENT_LEN;

    const int*   ent  = (const int*)  d_in[0];
    const float* Wsp  = (const float*)d_in[1];
    const float* bsp  = (const float*)d_in[2];
    const float* Wab  = (const float*)d_in[3];
    const float* bab  = (const float*)d_in[4];
    const float* Wit  = (const float*)d_in[5];
    const float* bit_ = (const float*)d_in[6];
    const float* Wmv  = (const float*)d_in[7];
    const float* bmv  = (const float*)d_in[8];
    const float* Wlv  = (const float*)d_in[9];
    const float* blv  = (const float*)d_in[10];
    const float* Whp  = (const float*)d_in[11];
    const float* bhp  = (const float*)d_in[12];
    const float* Wvo  = (const float*)d_in[13];
    const float* bvo  = (const float*)d_in[14];
    const float* Wft  = (const float*)d_in[15];
    const float* bft  = (const float*)d_in[16];
    const float* Wbo  = (const float*)d_in[17];
    const float* bbo  = (const float*)d_in[18];

    float* out_emb  = (float*)d_out;
    float* out_mask = out_emb + (size_t)n * D_DIM;

    if (ws_size >= WS_NEED) {
        unsigned short* T = (unsigned short*)d_ws;
        build_tables<<<R_TOTAL, 256, 0, stream>>>(
            Wsp, bsp, Wab, bab, Wit, bit_, Wmv, bmv, Wlv, blv,
            Whp, bhp, Wvo, bvo, Wft, bft, Wbo, bbo, T);
        encode_kernel<<<(n + 3) / 4, 256, 0, stream>>>(ent, T, out_emb, out_mask, n);
    } else {
        entity_encoder_fallback<<<(n + 1) / 2, 256, 0, stream>>>(
            ent, Wsp, bsp, Wab, bab, Wit, bit_, Wmv, bmv, Wlv, blv,
            Whp, bhp, Wvo, bvo, Wft, bft, Wbo, bbo, out_emb, out_mask, n);
    }
}

// Round 8
// 85.222 us; speedup vs baseline: 1.3137x; 1.3137x over previous
//
#include <hip/hip_runtime.h>

namespace {

constexpr int D_DIM   = 512;
constexpr int ENT_LEN = 39;

typedef __attribute__((ext_vector_type(4))) float f32x4;
typedef __attribute__((ext_vector_type(2))) float f32x2;

// ---- fused bf16 table row offsets (rows of 512 bf16 = 1 KB each) ----
constexpr int R_SP    = 0;                 // 1280: W_species[r] + sum(all 9 biases)
constexpr int R_AB    = 1280;              // 320
constexpr int R_IT    = 1600;              // 1024
constexpr int R_MV    = 2624;              // 1792: mv rows 0..895, pp rows 896..1791
constexpr int R_LV    = 4416;              // 101: bits(lv)@W_level + (lv/100)W_feats[0]
constexpr int R_HP    = 4517;              // 1024: bits(hp)@W_hp + (hp/1023)W_feats[1]
constexpr int R_VOL   = 5541;              // 4*256 pair tables
constexpr int R_V4TS  = 6565;              // 512: volcol8(16) x toxic(8) x sleep(4)
constexpr int R_BST   = 7077;              // 3*169 boost-pair tables
constexpr int R_B3GS  = 7584;              // 416: boost6(13) x gender(4) x status(8)
constexpr int R_FLAGS = 8000;              // 32: cb,trap,newsw,faint,active bits
constexpr int R_TOTAL = 8032;
constexpr size_t WS_NEED = (size_t)R_TOTAL * D_DIM * sizeof(unsigned short);

__device__ inline unsigned short f2bf(float f) {      // round-to-nearest-even
    unsigned u = __float_as_uint(f);
    u += 0x7fffu + ((u >> 16) & 1u);
    return (unsigned short)(u >> 16);
}

// ---------------- table precompute: 1 row per block, 2 dims per thread ----------------
__global__ __launch_bounds__(256) void build_tables(
    const float* __restrict__ Wsp, const float* __restrict__ bsp,
    const float* __restrict__ Wab, const float* __restrict__ bab,
    const float* __restrict__ Wit, const float* __restrict__ bit_,
    const float* __restrict__ Wmv, const float* __restrict__ bmv,
    const float* __restrict__ Wlv, const float* __restrict__ blv,
    const float* __restrict__ Whp, const float* __restrict__ bhp,
    const float* __restrict__ Wvo, const float* __restrict__ bvo,
    const float* __restrict__ Wft, const float* __restrict__ bft,
    const float* __restrict__ Wbo, const float* __restrict__ bbo,
    unsigned short* __restrict__ T)
{
    const int r = blockIdx.x;
    const int d = threadIdx.x << 1;
    float vx = 0.f, vy = 0.f;
    auto add = [&](const float* W, int row, float s) {
        const float2 w = *reinterpret_cast<const float2*>(W + (size_t)row * D_DIM + d);
        vx = fmaf(s, w.x, vx); vy = fmaf(s, w.y, vy);
    };
    if (r < R_AB) {
        add(Wsp, r, 1.f);
        add(bsp, 0, 1.f); add(bab, 0, 1.f); add(bit_, 0, 1.f);
        add(bmv, 0, 1.f); add(blv, 0, 1.f); add(bhp, 0, 1.f);
        add(bvo, 0, 1.f); add(bft, 0, 1.f); add(bbo, 0, 1.f);
    } else if (r < R_IT) {
        add(Wab, r - R_AB, 1.f);
    } else if (r < R_MV) {
        add(Wit, r - R_IT, 1.f);
    } else if (r < R_LV) {
        add(Wmv, r - R_MV, 1.f);             // rows 0..895 = mv, 896..1791 = pp
    } else if (r < R_HP) {
        const int lv = r - R_LV;
        for (int b = 0; b < 7; ++b) if ((lv >> b) & 1) add(Wlv, b, 1.f);
        add(Wft, 0, (float)lv * (1.f / 100.f));
    } else if (r < R_VOL) {
        const int hp = r - R_HP;
        for (int b = 0; b < 10; ++b) if ((hp >> b) & 1) add(Whp, b, 1.f);
        add(Wft, 1, (float)hp * (1.f / 1023.f));
    } else if (r < R_V4TS) {
        const int rr = r - R_VOL;              // pair table p: code = v[2p] | v[2p+1]<<4
        const int p = rr >> 8, code = rr & 255, va = code & 15, vb = code >> 4;
        for (int b = 0; b < 4; ++b) {
            if ((va >> b) & 1) add(Wvo, 8 * p + b, 1.f);
            if ((vb >> b) & 1) add(Wvo, 8 * p + 4 + b, 1.f);
        }
    } else if (r < R_BST) {
        const int rr = r - R_V4TS;             // v8(4b) | (tox*4+sl)<<4
        const int v8 = rr & 15, ts = rr >> 4, tox = ts >> 2, sl = ts & 3;
        for (int b = 0; b < 4; ++b) if ((v8 >> b) & 1) add(Wvo, 32 + b, 1.f);
        add(Wbo, 18 + tox, 1.f);
        add(Wbo, 26 + sl, 1.f);
    } else if (r < R_B3GS) {
        const int rr = r - R_BST;              // pair q: code = ba + 13*bb
        const int q = rr / 169, code = rr % 169, ba = code % 13, bb = code / 13;
        add(Wbo, 34 + 26 * q + ba, 1.f);
        add(Wbo, 34 + 26 * q + 13 + bb, 1.f);
        add(Wft, 2 + 2 * q, 0.5f * (float)(ba - 6));
        add(Wft, 3 + 2 * q, 0.5f * (float)(bb - 6));
    } else if (r < R_FLAGS) {
        const int rr = r - R_B3GS;             // b6 + 13*(g*8+s)
        const int b6 = rr % 13, gs = rr / 13, g = gs >> 3, s = gs & 7;
        add(Wbo, 34 + 78 + b6, 1.f);
        add(Wft, 8, 0.5f * (float)(b6 - 6));
        add(Wbo, g, 1.f);
        add(Wbo, 4 + s, 1.f);
    } else {
        const int code = r - R_FLAGS;          // cb*16+tr*8+ns*4+fa*2+ac
        add(Wbo, 12 + ((code >> 4) & 1), 1.f);
        add(Wbo, 14 + ((code >> 3) & 1), 1.f);
        add(Wbo, 16 + ((code >> 2) & 1), 1.f);
        add(Wbo, 30 + ((code >> 1) & 1), 1.f);
        add(Wbo, 32 + (code & 1), 1.f);
    }
    ushort2 o; o.x = f2bf(vx); o.y = f2bf(vy);
    *reinterpret_cast<ushort2*>(T + (size_t)r * D_DIM + d) = o;
}

// -------- main encode (r4-v2): 1 wave = 2 entities x one D-half --------
// lanes 0-31 -> entity A, 32-63 -> entity B; 23 dwordx4 loads of 1 KB each.
// Half-0 waves dispatch first -> live table set ~4.1 MB ~ per-XCD L2.
// Row offsets on SALU; per-lane select = 2 VALU (v_and + v_add3).
__global__ __launch_bounds__(256, 4) void encode_kernel(
    const int* __restrict__ ent, const unsigned short* __restrict__ T,
    float* __restrict__ out_emb, float* __restrict__ out_mask, int n)
{
    const int nP = (n + 1) >> 1;
    const int w = (blockIdx.x << 2) | (threadIdx.x >> 6);   // wave id in [0, 2*nP)
    const int half = (w >= nP) ? 1 : 0;
    const int p0 = w - (half ? nP : 0);
    if (p0 >= nP) return;
    const int pu = __builtin_amdgcn_readfirstlane(p0);
    const int eA = 2 * pu;
    const int eB = (eA + 1 < n) ? eA + 1 : eA;              // odd-n guard (benign dup)
    const int* __restrict__ ea = ent + (size_t)eA * ENT_LEN;  // uniform -> s_load
    const int* __restrict__ eb = ent + (size_t)eB * ENT_LEN;

    const int lane = threadIdx.x & 63;
    const unsigned lmask = (lane >= 32) ? 0xFFFFFFFFu : 0u;  // B-group mask
    // per-lane constant part of the offset: half*512 + (lane&31)*16
    const unsigned vbase = ((unsigned)half << 9) + ((unsigned)(lane & 31) << 4);
    const char* __restrict__ Tb = reinterpret_cast<const char*>(T);

    auto SEL = [&](unsigned a, unsigned b) -> unsigned { return a + ((b - a) & lmask); };
    // voff = rowSel*1024 + vbase   (rowA/rowB, diff on SALU; 2 VALU per load)
    auto LDP = [&](int rowA, int rowB) -> uint4 {
        const unsigned offA = (unsigned)rowA << 10;
        const unsigned offB = (unsigned)rowB << 10;
        const unsigned voff = offA + ((offB - offA) & lmask) + vbase;
        return *reinterpret_cast<const uint4*>(Tb + voff);
    };

    // ---- row indices for both entities (SALU) ----
    const int spA = ea[0],  spB = eb[0];
    const int mvA0 = ea[21], mvA1 = ea[22], mvA2 = ea[23], mvA3 = ea[24];
    const int mvB0 = eb[21], mvB1 = eb[22], mvB2 = eb[23], mvB3 = eb[24];

    // ---- 23 loads (1 KB each) ----
    const uint4 uSP = LDP(R_SP + spA, R_SP + spB);
    const uint4 uAB = LDP(R_AB + ea[1], R_AB + eb[1]);
    const uint4 uIT = LDP(R_IT + ea[2], R_IT + eb[2]);
    const uint4 uM0 = LDP(R_MV + mvA0, R_MV + mvB0);
    const uint4 uM1 = LDP(R_MV + mvA1, R_MV + mvB1);
    const uint4 uM2 = LDP(R_MV + mvA2, R_MV + mvB2);
    const uint4 uM3 = LDP(R_MV + mvA3, R_MV + mvB3);
    const uint4 uP0 = LDP(R_MV + 896 + mvA0, R_MV + 896 + mvB0);
    const uint4 uP1 = LDP(R_MV + 896 + mvA1, R_MV + 896 + mvB1);
    const uint4 uP2 = LDP(R_MV + 896 + mvA2, R_MV + 896 + mvB2);
    const uint4 uP3 = LDP(R_MV + 896 + mvA3, R_MV + 896 + mvB3);
    const uint4 uLV = LDP(R_LV + ea[3], R_LV + eb[3]);
    const uint4 uHP = LDP(R_HP + ea[4], R_HP + eb[4]);
    const uint4 uV0 = LDP(R_VOL + (0 << 8) + (ea[30] | (ea[31] << 4)),
                          R_VOL + (0 << 8) + (eb[30] | (eb[31] << 4)));
    const uint4 uV1 = LDP(R_VOL + (1 << 8) + (ea[32] | (ea[33] << 4)),
                          R_VOL + (1 << 8) + (eb[32] | (eb[33] << 4)));
    const uint4 uV2 = LDP(R_VOL + (2 << 8) + (ea[34] | (ea[35] << 4)),
                          R_VOL + (2 << 8) + (eb[34] | (eb[35] << 4)));
    const uint4 uV3 = LDP(R_VOL + (3 << 8) + (ea[36] | (ea[37] << 4)),
                          R_VOL + (3 << 8) + (eb[36] | (eb[37] << 4)));
    const uint4 uVT = LDP(R_V4TS + ea[38] + (((ea[10] << 2) + ea[11]) << 4),
                          R_V4TS + eb[38] + (((eb[10] << 2) + eb[11]) << 4));
    const uint4 uB0 = LDP(R_BST + 0 * 169 + (ea[14] + 6) + 13 * (ea[15] + 6),
                          R_BST + 0 * 169 + (eb[14] + 6) + 13 * (eb[15] + 6));
    const uint4 uB1 = LDP(R_BST + 1 * 169 + (ea[16] + 6) + 13 * (ea[17] + 6),
                          R_BST + 1 * 169 + (eb[16] + 6) + 13 * (eb[17] + 6));
    const uint4 uB2 = LDP(R_BST + 2 * 169 + (ea[18] + 6) + 13 * (ea[19] + 6),
                          R_BST + 2 * 169 + (eb[18] + 6) + 13 * (eb[19] + 6));
    const uint4 uBG = LDP(R_B3GS + (ea[20] + 6) + 13 * ((ea[5] << 3) + ea[6]),
                          R_B3GS + (eb[20] + 6) + 13 * ((eb[5] << 3) + eb[6]));
    const uint4 uFL = LDP(R_FLAGS + (ea[7] << 4) + (ea[8] << 3) + (ea[9] << 2) +
                              (ea[12] << 1) + ea[13],
                          R_FLAGS + (eb[7] << 4) + (eb[8] << 3) + (eb[9] << 2) +
                              (eb[12] << 1) + eb[13]);

    // pp scales: per-lane select of the integer, then convert (cheap)
    const float s0 = (float)(int)SEL((unsigned)ea[25], (unsigned)eb[25]) * (1.f / 1023.f);
    const float s1 = (float)(int)SEL((unsigned)ea[26], (unsigned)eb[26]) * (1.f / 1023.f);
    const float s2 = (float)(int)SEL((unsigned)ea[27], (unsigned)eb[27]) * (1.f / 1023.f);
    const float s3 = (float)(int)SEL((unsigned)ea[28], (unsigned)eb[28]) * (1.f / 1023.f);

    // ---- accumulate: f32x2 -> v_pk_add_f32 / v_pk_fma_f32 ----
    f32x2 c0 = {0.f, 0.f}, c1 = {0.f, 0.f}, c2 = {0.f, 0.f}, c3 = {0.f, 0.f};
    auto UNP = [](unsigned u) -> f32x2 {   // lo exact via shift; hi contaminated (<=2^-8 rel)
        f32x2 r; r.x = __uint_as_float(u << 16); r.y = __uint_as_float(u); return r;
    };
    auto A4 = [&](uint4 u) {
        c0 += UNP(u.x); c1 += UNP(u.y); c2 += UNP(u.z); c3 += UNP(u.w);
    };
    auto F4 = [&](uint4 u, float s) {
        const f32x2 sv = {s, s};
        c0 = __builtin_elementwise_fma(UNP(u.x), sv, c0);
        c1 = __builtin_elementwise_fma(UNP(u.y), sv, c1);
        c2 = __builtin_elementwise_fma(UNP(u.z), sv, c2);
        c3 = __builtin_elementwise_fma(UNP(u.w), sv, c3);
    };

    A4(uSP); A4(uAB); A4(uIT);
    A4(uM0); A4(uM1); A4(uM2); A4(uM3);
    F4(uP0, s0); F4(uP1, s1); F4(uP2, s2); F4(uP3, s3);
    A4(uLV); A4(uHP);
    A4(uV0); A4(uV1); A4(uV2); A4(uV3); A4(uVT);
    A4(uB0); A4(uB1); A4(uB2); A4(uBG);
    A4(uFL);

    const int sp_l = (int)SEL((unsigned)spA, (unsigned)spB);
    const float msk = (sp_l > 1) ? 1.f : 0.f;
    const int e_l = (int)SEL((unsigned)eA, (unsigned)eB);
    const f32x2 mk = {msk, msk};
    c0 *= mk; c1 *= mk; c2 *= mk; c3 *= mk;

    // lane covers 8 consecutive f32 dims: d = half*256 + (lane&31)*8
    f32x4 o0 = {c0.x, c0.y, c1.x, c1.y};
    f32x4 o1 = {c2.x, c2.y, c3.x, c3.y};
    float* op = out_emb + (size_t)e_l * D_DIM + ((unsigned)half << 8) + ((unsigned)(lane & 31) << 3);
    __builtin_nontemporal_store(o0, reinterpret_cast<f32x4*>(op));
    __builtin_nontemporal_store(o1, reinterpret_cast<f32x4*>(op + 4));
    if (half == 0 && (lane & 31) == 0) out_mask[e_l] = msk;
}

// ---------------- fallback (round-0 kernel) if workspace is too small ----------------
__global__ __launch_bounds__(256) void entity_encoder_fallback(
    const int*   __restrict__ ent,
    const float* __restrict__ W_species, const float* __restrict__ b_species,
    const float* __restrict__ W_ability, const float* __restrict__ b_ability,
    const float* __restrict__ W_item,    const float* __restrict__ b_item,
    const float* __restrict__ W_moveset, const float* __restrict__ b_moveset,
    const float* __restrict__ W_level,   const float* __restrict__ b_level,
    const float* __restrict__ W_hp,      const float* __restrict__ b_hp,
    const float* __restrict__ W_vol,     const float* __restrict__ b_vol,
    const float* __restrict__ W_feats,   const float* __restrict__ b_feats,
    const float* __restrict__ W_bool,    const float* __restrict__ b_bool,
    float* __restrict__ out_emb, float* __restrict__ out_mask, int n)
{
    const int e_idx = (blockIdx.x << 1) | (threadIdx.x >> 7);
    if (e_idx >= n) return;
    const int t = threadIdx.x & 127;
    const int d = t << 2;
    const int* __restrict__ e = ent + e_idx * ENT_LEN;
    float4 acc = make_float4(0.f, 0.f, 0.f, 0.f);
#define ADDROW(W, row) do {                                                        \
        const float4 v_ = *reinterpret_cast<const float4*>((W) + ((size_t)(row))*D_DIM + d); \
        acc.x += v_.x; acc.y += v_.y; acc.z += v_.z; acc.w += v_.w;                \
    } while (0)
#define FMAROW(W, row, s) do {                                                     \
        const float4 v_ = *reinterpret_cast<const float4*>((W) + ((size_t)(row))*D_DIM + d); \
        const float s_ = (s);                                                      \
        acc.x = fmaf(s_, v_.x, acc.x); acc.y = fmaf(s_, v_.y, acc.y);              \
        acc.z = fmaf(s_, v_.z, acc.z); acc.w = fmaf(s_, v_.w, acc.w);              \
    } while (0)
    const int sp = e[0];
    ADDROW(W_species, sp); ADDROW(W_ability, e[1]); ADDROW(W_item, e[2]);
    #pragma unroll
    for (int m = 0; m < 4; ++m) {
        const int mv = e[21 + m];
        ADDROW(W_moveset, mv);
        FMAROW(W_moveset, 896 + mv, (float)e[25 + m] * (1.0f / 1023.0f));
    }
    const int lv = e[3];
    #pragma unroll
    for (int b = 0; b < 7; ++b) if ((lv >> b) & 1) ADDROW(W_level, b);
    const int hp = e[4];
    #pragma unroll
    for (int b = 0; b < 10; ++b) if ((hp >> b) & 1) ADDROW(W_hp, b);
    #pragma unroll
    for (int j = 0; j < 9; ++j) {
        const int v = e[30 + j];
        #pragma unroll
        for (int b = 0; b < 4; ++b) if ((v >> b) & 1) ADDROW(W_vol, j * 4 + b);
    }
    FMAROW(W_feats, 0, (float)lv * (1.0f / 100.0f));
    FMAROW(W_feats, 1, (float)hp * (1.0f / 1023.0f));
    #pragma unroll
    for (int i = 0; i < 7; ++i) FMAROW(W_feats, 2 + i, 0.5f * (float)e[14 + i]);
    ADDROW(W_bool, e[5]); ADDROW(W_bool, 4 + e[6]); ADDROW(W_bool, 12 + e[7]);
    ADDROW(W_bool, 14 + e[8]); ADDROW(W_bool, 16 + e[9]); ADDROW(W_bool, 18 + e[10]);
    ADDROW(W_bool, 26 + e[11]); ADDROW(W_bool, 30 + e[12]); ADDROW(W_bool, 32 + e[13]);
    #pragma unroll
    for (int i = 0; i < 7; ++i) ADDROW(W_bool, 34 + 13 * i + e[14 + i] + 6);
    ADDROW(b_species, 0); ADDROW(b_ability, 0); ADDROW(b_item, 0);
    ADDROW(b_moveset, 0); ADDROW(b_level, 0);   ADDROW(b_hp, 0);
    ADDROW(b_vol, 0);     ADDROW(b_feats, 0);   ADDROW(b_bool, 0);
#undef ADDROW
#undef FMAROW
    const bool mask = !(sp == 0 || sp == 1);
    if (!mask) acc = make_float4(0.f, 0.f, 0.f, 0.f);
    *reinterpret_cast<float4*>(out_emb + (size_t)e_idx * D_DIM + d) = acc;
    if (t == 0) out_mask[e_idx] = mask ? 1.0f : 0.0f;
}

} // namespace

extern "C" void kernel_launch(void* const* d_in, const int* in_sizes, int n_in,
                              void* d_out, int out_size, void* d_ws, size_t ws_size,
                              hipStream_t stream) {
    const int n = in_sizes[0] / ENT_LEN;

    const int*   ent  = (const int*)  d_in[0];
    const float* Wsp  = (const float*)d_in[1];
    const float* bsp  = (const float*)d_in[2];
    const float* Wab  = (const float*)d_in[3];
    const float* bab  = (const float*)d_in[4];
    const float* Wit  = (const float*)d_in[5];
    const float* bit_ = (const float*)d_in[6];
    const float* Wmv  = (const float*)d_in[7];
    const float* bmv  = (const float*)d_in[8];
    const float* Wlv  = (const float*)d_in[9];
    const float* blv  = (const float*)d_in[10];
    const float* Whp  = (const float*)d_in[11];
    const float* bhp  = (const float*)d_in[12];
    const float* Wvo  = (const float*)d_in[13];
    const float* bvo  = (const float*)d_in[14];
    const float* Wft  = (const float*)d_in[15];
    const float* bft  = (const float*)d_in[16];
    const float* Wbo  = (const float*)d_in[17];
    const float* bbo  = (const float*)d_in[18];

    float* out_emb  = (float*)d_out;
    float* out_mask = out_emb + (size_t)n * D_DIM;

    if (ws_size >= WS_NEED) {
        unsigned short* T = (unsigned short*)d_ws;
        build_tables<<<R_TOTAL, 256, 0, stream>>>(
            Wsp, bsp, Wab, bab, Wit, bit_, Wmv, bmv, Wlv, blv,
            Whp, bhp, Wvo, bvo, Wft, bft, Wbo, bbo, T);
        const int nP = (n + 1) >> 1;
        const int waves = 2 * nP;                      // (pair, half)
        encode_kernel<<<(waves + 3) / 4, 256, 0, stream>>>(ent, T, out_emb, out_mask, n);
    } else {
        entity_encoder_fallback<<<(n + 1) / 2, 256, 0, stream>>>(
            ent, Wsp, bsp, Wab, bab, Wit, bit_, Wmv, bmv, Wlv, blv,
            Whp, bhp, Wvo, bvo, Wft, bft, Wbo, bbo, out_emb, out_mask, n);
    }
}

// Round 9
// 75.989 us; speedup vs baseline: 1.4733x; 1.1215x over previous
//
#include <hip/hip_runtime.h>

namespace {

constexpr int D_DIM   = 512;
constexpr int ENT_LEN = 39;

typedef __attribute__((ext_vector_type(4))) float f32x4;
typedef __attribute__((ext_vector_type(2))) float f32x2;

// ================= table layout =================
// fp8 region (rows of 512 B, scale x16, e4m3fn):
constexpr int P_SP  = 0;      // 1280: W_species[r] + sum(all 9 biases)
constexpr int P_AB  = 1280;   // 320
constexpr int P_IT  = 1600;   // 1024
constexpr int P_MV  = 2624;   // 1792: mv 0..895, pp 896..1791
constexpr int P_CNT = 4416;
// bf16 region (rows of 1024 B), region-local row ids:
constexpr int Q_LV  = 0;      // 101: bits(lv)@W_level + (lv/100)W_feats[0]
constexpr int Q_HP  = 101;    // 1024
constexpr int Q_VOL = 1125;   // 4*256 pair tables
constexpr int Q_VTS = 2149;   // 512: volcol8(16) x toxic(8) x sleep(4)
constexpr int Q_BST = 2661;   // 3*169 boost-pair tables
constexpr int Q_BGS = 3168;   // 416: boost6(13) x gender(4) x status(8)
constexpr int Q_FL  = 3584;   // 32: cb,trap,newsw,faint,active
constexpr int Q_CNT = 3616;

constexpr unsigned BO_BF = (unsigned)P_CNT * 512;                 // 2260992
constexpr size_t   WS_NEED = (size_t)BO_BF + (size_t)Q_CNT * 1024;
constexpr float    FP8_SCALE = 16.f;
constexpr float    FP8_INV   = 1.f / 16.f;

__device__ inline unsigned short f2bf(float f) {      // round-to-nearest-even
    unsigned u = __float_as_uint(f);
    u += 0x7fffu + ((u >> 16) & 1u);
    return (unsigned short)(u >> 16);
}

// float -> OCP e4m3fn, RNE, satfinite (values pre-scaled by 16; |v| << 448)
__device__ inline unsigned char f2fp8(float f) {
    unsigned u = __float_as_uint(f);
    const unsigned s = (u >> 24) & 0x80u;
    const float af = __uint_as_float(u & 0x7fffffffu);
    if (af >= 448.f) return (unsigned char)(s | 0x7E);          // clamp to 448
    if (af < 0.001953125f) {                                    // < 2^-9
        const int q = (int)rintf(af * 512.f);                   // 0 or 1
        return (unsigned char)(s | (unsigned)q);
    }
    u = __float_as_uint(af);
    int e = (int)((u >> 23) & 0xFF) - 127;
    if (e < -6) {                                               // subnormal: m * 2^-9
        const int q = (int)rintf(af * 512.f);                   // 1..8
        return (unsigned char)(s | (unsigned)q);                // q==8 -> 0x08 = 2^-6
    }
    u += 0x7FFFFu + ((u >> 20) & 1u);                           // RNE at 3 mantissa bits
    e = (int)((u >> 23) & 0xFF) - 127;
    if (e > 8) return (unsigned char)(s | 0x7E);
    const unsigned m = (u >> 20) & 0x7u;
    return (unsigned char)(s | ((unsigned)(e + 7) << 3) | m);
}

// ---------------- table precompute: 1 row per block, 2 dims per thread ----------------
__global__ __launch_bounds__(256) void build_tables(
    const float* __restrict__ Wsp, const float* __restrict__ bsp,
    const float* __restrict__ Wab, const float* __restrict__ bab,
    const float* __restrict__ Wit, const float* __restrict__ bit_,
    const float* __restrict__ Wmv, const float* __restrict__ bmv,
    const float* __restrict__ Wlv, const float* __restrict__ blv,
    const float* __restrict__ Whp, const float* __restrict__ bhp,
    const float* __restrict__ Wvo, const float* __restrict__ bvo,
    const float* __restrict__ Wft, const float* __restrict__ bft,
    const float* __restrict__ Wbo, const float* __restrict__ bbo,
    unsigned char* __restrict__ T)
{
    const int r = blockIdx.x;
    const int d = threadIdx.x << 1;
    float vx = 0.f, vy = 0.f;
    auto add = [&](const float* W, int row, float s) {
        const float2 w = *reinterpret_cast<const float2*>(W + (size_t)row * D_DIM + d);
        vx = fmaf(s, w.x, vx); vy = fmaf(s, w.y, vy);
    };

    if (r < P_CNT) {
        // ---------- fp8 rows ----------
        if (r < P_AB) {
            add(Wsp, r, 1.f);
            add(bsp, 0, 1.f); add(bab, 0, 1.f); add(bit_, 0, 1.f);
            add(bmv, 0, 1.f); add(blv, 0, 1.f); add(bhp, 0, 1.f);
            add(bvo, 0, 1.f); add(bft, 0, 1.f); add(bbo, 0, 1.f);
        } else if (r < P_IT) {
            add(Wab, r - P_AB, 1.f);
        } else if (r < P_MV) {
            add(Wit, r - P_IT, 1.f);
        } else {
            add(Wmv, r - P_MV, 1.f);          // 0..895 mv, 896..1791 pp
        }
        uchar2 o;
        o.x = f2fp8(vx * FP8_SCALE);
        o.y = f2fp8(vy * FP8_SCALE);
        *reinterpret_cast<uchar2*>(T + (size_t)r * 512 + d) = o;
        return;
    }

    // ---------- bf16 rows ----------
    const int rb = r - P_CNT;
    if (rb < Q_HP) {
        const int lv = rb - Q_LV;
        for (int b = 0; b < 7; ++b) if ((lv >> b) & 1) add(Wlv, b, 1.f);
        add(Wft, 0, (float)lv * (1.f / 100.f));
    } else if (rb < Q_VOL) {
        const int hp = rb - Q_HP;
        for (int b = 0; b < 10; ++b) if ((hp >> b) & 1) add(Whp, b, 1.f);
        add(Wft, 1, (float)hp * (1.f / 1023.f));
    } else if (rb < Q_VTS) {
        const int rr = rb - Q_VOL;             // pair table p: code = v[2p] | v[2p+1]<<4
        const int p = rr >> 8, code = rr & 255, va = code & 15, vb = code >> 4;
        for (int b = 0; b < 4; ++b) {
            if ((va >> b) & 1) add(Wvo, 8 * p + b, 1.f);
            if ((vb >> b) & 1) add(Wvo, 8 * p + 4 + b, 1.f);
        }
    } else if (rb < Q_BST) {
        const int rr = rb - Q_VTS;             // v8(4b) | (tox*4+sl)<<4
        const int v8 = rr & 15, ts = rr >> 4, tox = ts >> 2, sl = ts & 3;
        for (int b = 0; b < 4; ++b) if ((v8 >> b) & 1) add(Wvo, 32 + b, 1.f);
        add(Wbo, 18 + tox, 1.f);
        add(Wbo, 26 + sl, 1.f);
    } else if (rb < Q_BGS) {
        const int rr = rb - Q_BST;             // pair q: code = ba + 13*bb
        const int q = rr / 169, code = rr % 169, ba = code % 13, bb = code / 13;
        add(Wbo, 34 + 26 * q + ba, 1.f);
        add(Wbo, 34 + 26 * q + 13 + bb, 1.f);
        add(Wft, 2 + 2 * q, 0.5f * (float)(ba - 6));
        add(Wft, 3 + 2 * q, 0.5f * (float)(bb - 6));
    } else if (rb < Q_FL) {
        const int rr = rb - Q_BGS;             // b6 + 13*(g*8+s)
        const int b6 = rr % 13, gs = rr / 13, g = gs >> 3, s = gs & 7;
        add(Wbo, 34 + 78 + b6, 1.f);
        add(Wft, 8, 0.5f * (float)(b6 - 6));
        add(Wbo, g, 1.f);
        add(Wbo, 4 + s, 1.f);
    } else {
        const int code = rb - Q_FL;            // cb*16+tr*8+ns*4+fa*2+ac
        add(Wbo, 12 + ((code >> 4) & 1), 1.f);
        add(Wbo, 14 + ((code >> 3) & 1), 1.f);
        add(Wbo, 16 + ((code >> 2) & 1), 1.f);
        add(Wbo, 30 + ((code >> 1) & 1), 1.f);
        add(Wbo, 32 + (code & 1), 1.f);
    }
    ushort2 o; o.x = f2bf(vx); o.y = f2bf(vy);
    *reinterpret_cast<ushort2*>(T + BO_BF + (size_t)rb * 1024 + d * 2) = o;
}

// -------- main encode: 1 wave = 2 entities x one D-half (r8 shape) --------
// 11 fp8 dwordx2 loads + 12 bf16 dwordx4 loads = 17.5 KB/entity (-24% vs r8).
// Live half-set 2.85 MB < 4 MB per-XCD L2.
__global__ __launch_bounds__(256, 4) void encode_kernel(
    const int* __restrict__ ent, const unsigned char* __restrict__ T,
    float* __restrict__ out_emb, float* __restrict__ out_mask, int n)
{
    const int nP = (n + 1) >> 1;
    const int w = (blockIdx.x << 2) | (threadIdx.x >> 6);   // wave id in [0, 2*nP)
    const int half = (w >= nP) ? 1 : 0;
    const int p0 = w - (half ? nP : 0);
    if (p0 >= nP) return;
    const int pu = __builtin_amdgcn_readfirstlane(p0);
    const int eA = 2 * pu;
    const int eB = (eA + 1 < n) ? eA + 1 : eA;              // odd-n guard (benign dup)
    const int* __restrict__ ea = ent + (size_t)eA * ENT_LEN;  // uniform -> s_load
    const int* __restrict__ eb = ent + (size_t)eB * ENT_LEN;

    const int lane = threadIdx.x & 63;
    const unsigned lmask = (lane >= 32) ? 0xFFFFFFFFu : 0u;  // B-group mask
    const unsigned vb16 = ((unsigned)half << 9) + ((unsigned)(lane & 31) << 4);
    const unsigned vb8  = ((unsigned)half << 8) + ((unsigned)(lane & 31) << 3);
    const char* __restrict__ Tb = reinterpret_cast<const char*>(T);

    auto SEL = [&](unsigned a, unsigned b) -> unsigned { return a + ((b - a) & lmask); };
    auto LDP16 = [&](unsigned rowA, unsigned rowB) -> uint4 {   // bf16 region-local rows
        const unsigned a = BO_BF + (rowA << 10);
        const unsigned b = BO_BF + (rowB << 10);
        const unsigned voff = a + ((b - a) & lmask) + vb16;
        return *reinterpret_cast<const uint4*>(Tb + voff);
    };
    auto LDP8 = [&](unsigned rowA, unsigned rowB) -> uint2 {    // fp8 rows (512 B)
        const unsigned a = rowA << 9;
        const unsigned b = rowB << 9;
        const unsigned voff = a + ((b - a) & lmask) + vb8;
        return *reinterpret_cast<const uint2*>(Tb + voff);
    };

    // ---- row indices for both entities (SALU) ----
    const int spA = ea[0],  spB = eb[0];
    const int mvA0 = ea[21], mvA1 = ea[22], mvA2 = ea[23], mvA3 = ea[24];
    const int mvB0 = eb[21], mvB1 = eb[22], mvB2 = eb[23], mvB3 = eb[24];

    // ---- issue all 23 loads ----
    const uint2 uSP = LDP8(P_SP + spA, P_SP + spB);
    const uint2 uAB = LDP8(P_AB + ea[1], P_AB + eb[1]);
    const uint2 uIT = LDP8(P_IT + ea[2], P_IT + eb[2]);
    const uint2 uM0 = LDP8(P_MV + mvA0, P_MV + mvB0);
    const uint2 uM1 = LDP8(P_MV + mvA1, P_MV + mvB1);
    const uint2 uM2 = LDP8(P_MV + mvA2, P_MV + mvB2);
    const uint2 uM3 = LDP8(P_MV + mvA3, P_MV + mvB3);
    const uint2 uP0 = LDP8(P_MV + 896 + mvA0, P_MV + 896 + mvB0);
    const uint2 uP1 = LDP8(P_MV + 896 + mvA1, P_MV + 896 + mvB1);
    const uint2 uP2 = LDP8(P_MV + 896 + mvA2, P_MV + 896 + mvB2);
    const uint2 uP3 = LDP8(P_MV + 896 + mvA3, P_MV + 896 + mvB3);
    const uint4 uLV = LDP16(Q_LV + ea[3], Q_LV + eb[3]);
    const uint4 uHP = LDP16(Q_HP + ea[4], Q_HP + eb[4]);
    const uint4 uV0 = LDP16(Q_VOL + (0 << 8) + (ea[30] | (ea[31] << 4)),
                            Q_VOL + (0 << 8) + (eb[30] | (eb[31] << 4)));
    const uint4 uV1 = LDP16(Q_VOL + (1 << 8) + (ea[32] | (ea[33] << 4)),
                            Q_VOL + (1 << 8) + (eb[32] | (eb[33] << 4)));
    const uint4 uV2 = LDP16(Q_VOL + (2 << 8) + (ea[34] | (ea[35] << 4)),
                            Q_VOL + (2 << 8) + (eb[34] | (eb[35] << 4)));
    const uint4 uV3 = LDP16(Q_VOL + (3 << 8) + (ea[36] | (ea[37] << 4)),
                            Q_VOL + (3 << 8) + (eb[36] | (eb[37] << 4)));
    const uint4 uVT = LDP16(Q_VTS + ea[38] + (((ea[10] << 2) + ea[11]) << 4),
                            Q_VTS + eb[38] + (((eb[10] << 2) + eb[11]) << 4));
    const uint4 uB0 = LDP16(Q_BST + 0 * 169 + (ea[14] + 6) + 13 * (ea[15] + 6),
                            Q_BST + 0 * 169 + (eb[14] + 6) + 13 * (eb[15] + 6));
    const uint4 uB1 = LDP16(Q_BST + 1 * 169 + (ea[16] + 6) + 13 * (ea[17] + 6),
                            Q_BST + 1 * 169 + (eb[16] + 6) + 13 * (eb[17] + 6));
    const uint4 uB2 = LDP16(Q_BST + 2 * 169 + (ea[18] + 6) + 13 * (ea[19] + 6),
                            Q_BST + 2 * 169 + (eb[18] + 6) + 13 * (eb[19] + 6));
    const uint4 uBG = LDP16(Q_BGS + (ea[20] + 6) + 13 * ((ea[5] << 3) + ea[6]),
                            Q_BGS + (eb[20] + 6) + 13 * ((eb[5] << 3) + eb[6]));
    const uint4 uFL = LDP16(Q_FL + (ea[7] << 4) + (ea[8] << 3) + (ea[9] << 2) +
                                (ea[12] << 1) + ea[13],
                            Q_FL + (eb[7] << 4) + (eb[8] << 3) + (eb[9] << 2) +
                                (eb[12] << 1) + eb[13]);

    // pp scales (x 1/16 fp8 descale folded in)
    const float s0 = (float)(int)SEL((unsigned)ea[25], (unsigned)eb[25]) * (FP8_INV / 1023.f);
    const float s1 = (float)(int)SEL((unsigned)ea[26], (unsigned)eb[26]) * (FP8_INV / 1023.f);
    const float s2 = (float)(int)SEL((unsigned)ea[27], (unsigned)eb[27]) * (FP8_INV / 1023.f);
    const float s3 = (float)(int)SEL((unsigned)ea[28], (unsigned)eb[28]) * (FP8_INV / 1023.f);

    // ---- accumulate: f32x2 -> v_pk_add_f32 / v_pk_fma_f32 ----
    f32x2 c0 = {0.f, 0.f}, c1 = {0.f, 0.f}, c2 = {0.f, 0.f}, c3 = {0.f, 0.f};

#if __has_builtin(__builtin_amdgcn_cvt_pk_f32_fp8)
    auto DECLO = [](unsigned dw) -> f32x2 {
        return __builtin_amdgcn_cvt_pk_f32_fp8((int)dw, false);
    };
    auto DECHI = [](unsigned dw) -> f32x2 {
        return __builtin_amdgcn_cvt_pk_f32_fp8((int)dw, true);
    };
#else
    auto DEC1 = [](unsigned b) -> float {
        const unsigned s = b >> 7, e = (b >> 3) & 15, m = b & 7;
        const float mag = e ? __uint_as_float(((e + 120u) << 23) | (m << 20))
                            : (float)m * (1.f / 512.f);
        return s ? -mag : mag;
    };
    auto DECLO = [DEC1](unsigned dw) -> f32x2 {
        f32x2 r; r.x = DEC1(dw & 255u); r.y = DEC1((dw >> 8) & 255u); return r;
    };
    auto DECHI = [DEC1](unsigned dw) -> f32x2 {
        f32x2 r; r.x = DEC1((dw >> 16) & 255u); r.y = DEC1(dw >> 24); return r;
    };
#endif

    auto UNP = [](unsigned u) -> f32x2 {   // bf16: lo exact via shift; hi contaminated
        f32x2 r; r.x = __uint_as_float(u << 16); r.y = __uint_as_float(u); return r;
    };
    auto A16 = [&](uint4 u) {
        c0 += UNP(u.x); c1 += UNP(u.y); c2 += UNP(u.z); c3 += UNP(u.w);
    };
    auto A8 = [&](uint2 u, float ws) {     // fp8 row, weight ws (1/16 or s/16)
        const f32x2 wv = {ws, ws};
        c0 = __builtin_elementwise_fma(DECLO(u.x), wv, c0);
        c1 = __builtin_elementwise_fma(DECHI(u.x), wv, c1);
        c2 = __builtin_elementwise_fma(DECLO(u.y), wv, c2);
        c3 = __builtin_elementwise_fma(DECHI(u.y), wv, c3);
    };

    A8(uSP, FP8_INV); A8(uAB, FP8_INV); A8(uIT, FP8_INV);
    A8(uM0, FP8_INV); A8(uM1, FP8_INV); A8(uM2, FP8_INV); A8(uM3, FP8_INV);
    A8(uP0, s0); A8(uP1, s1); A8(uP2, s2); A8(uP3, s3);
    A16(uLV); A16(uHP);
    A16(uV0); A16(uV1); A16(uV2); A16(uV3); A16(uVT);
    A16(uB0); A16(uB1); A16(uB2); A16(uBG);
    A16(uFL);

    const int sp_l = (int)SEL((unsigned)spA, (unsigned)spB);
    const float msk = (sp_l > 1) ? 1.f : 0.f;
    const int e_l = (int)SEL((unsigned)eA, (unsigned)eB);
    const f32x2 mk = {msk, msk};
    c0 *= mk; c1 *= mk; c2 *= mk; c3 *= mk;

    // lane covers 8 consecutive f32 dims: d = half*256 + (lane&31)*8
    f32x4 o0 = {c0.x, c0.y, c1.x, c1.y};
    f32x4 o1 = {c2.x, c2.y, c3.x, c3.y};
    float* op = out_emb + (size_t)e_l * D_DIM + ((unsigned)half << 8) + ((unsigned)(lane & 31) << 3);
    __builtin_nontemporal_store(o0, reinterpret_cast<f32x4*>(op));
    __builtin_nontemporal_store(o1, reinterpret_cast<f32x4*>(op + 4));
    if (half == 0 && (lane & 31) == 0) out_mask[e_l] = msk;
}

// ---------------- fallback (round-0 kernel) if workspace is too small ----------------
__global__ __launch_bounds__(256) void entity_encoder_fallback(
    const int*   __restrict__ ent,
    const float* __restrict__ W_species, const float* __restrict__ b_species,
    const float* __restrict__ W_ability, const float* __restrict__ b_ability,
    const float* __restrict__ W_item,    const float* __restrict__ b_item,
    const float* __restrict__ W_moveset, const float* __restrict__ b_moveset,
    const float* __restrict__ W_level,   const float* __restrict__ b_level,
    const float* __restrict__ W_hp,      const float* __restrict__ b_hp,
    const float* __restrict__ W_vol,     const float* __restrict__ b_vol,
    const float* __restrict__ W_feats,   const float* __restrict__ b_feats,
    const float* __restrict__ W_bool,    const float* __restrict__ b_bool,
    float* __restrict__ out_emb, float* __restrict__ out_mask, int n)
{
    const int e_idx = (blockIdx.x << 1) | (threadIdx.x >> 7);
    if (e_idx >= n) return;
    const int t = threadIdx.x & 127;
    const int d = t << 2;
    const int* __restrict__ e = ent + e_idx * ENT_LEN;
    float4 acc = make_float4(0.f, 0.f, 0.f, 0.f);
#define ADDROW(W, row) do {                                                        \
        const float4 v_ = *reinterpret_cast<const float4*>((W) + ((size_t)(row))*D_DIM + d); \
        acc.x += v_.x; acc.y += v_.y; acc.z += v_.z; acc.w += v_.w;                \
    } while (0)
#define FMAROW(W, row, s) do {                                                     \
        const float4 v_ = *reinterpret_cast<const float4*>((W) + ((size_t)(row))*D_DIM + d); \
        const float s_ = (s);                                                      \
        acc.x = fmaf(s_, v_.x, acc.x); acc.y = fmaf(s_, v_.y, acc.y);              \
        acc.z = fmaf(s_, v_.z, acc.z); acc.w = fmaf(s_, v_.w, acc.w);              \
    } while (0)
    const int sp = e[0];
    ADDROW(W_species, sp); ADDROW(W_ability, e[1]); ADDROW(W_item, e[2]);
    #pragma unroll
    for (int m = 0; m < 4; ++m) {
        const int mv = e[21 + m];
        ADDROW(W_moveset, mv);
        FMAROW(W_moveset, 896 + mv, (float)e[25 + m] * (1.0f / 1023.0f));
    }
    const int lv = e[3];
    #pragma unroll
    for (int b = 0; b < 7; ++b) if ((lv >> b) & 1) ADDROW(W_level, b);
    const int hp = e[4];
    #pragma unroll
    for (int b = 0; b < 10; ++b) if ((hp >> b) & 1) ADDROW(W_hp, b);
    #pragma unroll
    for (int j = 0; j < 9; ++j) {
        const int v = e[30 + j];
        #pragma unroll
        for (int b = 0; b < 4; ++b) if ((v >> b) & 1) ADDROW(W_vol, j * 4 + b);
    }
    FMAROW(W_feats, 0, (float)lv * (1.0f / 100.0f));
    FMAROW(W_feats, 1, (float)hp * (1.0f / 1023.0f));
    #pragma unroll
    for (int i = 0; i < 7; ++i) FMAROW(W_feats, 2 + i, 0.5f * (float)e[14 + i]);
    ADDROW(W_bool, e[5]); ADDROW(W_bool, 4 + e[6]); ADDROW(W_bool, 12 + e[7]);
    ADDROW(W_bool, 14 + e[8]); ADDROW(W_bool, 16 + e[9]); ADDROW(W_bool, 18 + e[10]);
    ADDROW(W_bool, 26 + e[11]); ADDROW(W_bool, 30 + e[12]); ADDROW(W_bool, 32 + e[13]);
    #pragma unroll
    for (int i = 0; i < 7; ++i) ADDROW(W_bool, 34 + 13 * i + e[14 + i] + 6);
    ADDROW(b_species, 0); ADDROW(b_ability, 0); ADDROW(b_item, 0);
    ADDROW(b_moveset, 0); ADDROW(b_level, 0);   ADDROW(b_hp, 0);
    ADDROW(b_vol, 0);     ADDROW(b_feats, 0);   ADDROW(b_bool, 0);
#undef ADDROW
#undef FMAROW
    const bool mask = !(sp == 0 || sp == 1);
    if (!mask) acc = make_float4(0.f, 0.f, 0.f, 0.f);
    *reinterpret_cast<float4*>(out_emb + (size_t)e_idx * D_DIM + d) = acc;
    if (t == 0) out_mask[e_idx] = mask ? 1.0f : 0.0f;
}

} // namespace

extern "C" void kernel_launch(void* const* d_in, const int* in_sizes, int n_in,
                              void* d_out, int out_size, void* d_ws, size_t ws_size,
                              hipStream_t stream) {
    const int n = in_sizes[0] / ENT_LEN;

    const int*   ent  = (const int*)  d_in[0];
    const float* Wsp  = (const float*)d_in[1];
    const float* bsp  = (const float*)d_in[2];
    const float* Wab  = (const float*)d_in[3];
    const float* bab  = (const float*)d_in[4];
    const float* Wit  = (const float*)d_in[5];
    const float* bit_ = (const float*)d_in[6];
    const float* Wmv  = (const float*)d_in[7];
    const float* bmv  = (const float*)d_in[8];
    const float* Wlv  = (const float*)d_in[9];
    const float* blv  = (const float*)d_in[10];
    const float* Whp  = (const float*)d_in[11];
    const float* bhp  = (const float*)d_in[12];
    const float* Wvo  = (const float*)d_in[13];
    const float* bvo  = (const float*)d_in[14];
    const float* Wft  = (const float*)d_in[15];
    const float* bft  = (const float*)d_in[16];
    const float* Wbo  = (const float*)d_in[17];
    const float* bbo  = (const float*)d_in[18];

    float* out_emb  = (float*)d_out;
    float* out_mask = out_emb + (size_t)n * D_DIM;

    if (ws_size >= WS_NEED) {
        unsigned char* T = (unsigned char*)d_ws;
        build_tables<<<P_CNT + Q_CNT, 256, 0, stream>>>(
            Wsp, bsp, Wab, bab, Wit, bit_, Wmv, bmv, Wlv, blv,
            Whp, bhp, Wvo, bvo, Wft, bft, Wbo, bbo, T);
        const int nP = (n + 1) >> 1;
        const int waves = 2 * nP;                      // (pair, half)
        encode_kernel<<<(waves + 3) / 4, 256, 0, stream>>>(ent, T, out_emb, out_mask, n);
    } else {
        entity_encoder_fallback<<<(n + 1) / 2, 256, 0, stream>>>(
            ent, Wsp, bsp, Wab, bab, Wit, bit_, Wmv, bmv, Wlv, blv,
            Whp, bhp, Wvo, bvo, Wft, bft, Wbo, bbo, out_emb, out_mask, n);
    }
}